// Round 11
// baseline (225.461 us; speedup 1.0000x reference)
//
#include <hip/hip_runtime.h>
#include <stdint.h>

// B=4 N=32 L=S=256 H=8 E=D=64
// R10: grid 2048 x 512 threads (8 waves). Each block = (bnh, q-half of 128
// rows). Pair blocks of one bnh land on the SAME XCD adjacent in dispatch
// order (b and b+8) so the second's K/V fetch hits XCD L2. 3 blocks/CU
// target (launch_bounds(512,6) -> <=85 total regs incl AGPR) = 24 waves/CU,
// phase-heterogeneous (no CU-wide lockstep). Per-tile K/V slice staging,
// raw lgkmcnt-only barriers, named staging regs -- all R9-verified.
// Half-0 blocks skip V staging for s-tiles > 3 (PV never reads them).
// 8-wave q-tile perm [0,1,2,3,6,7,4,5]: PV cost balanced per SIMD pair.

typedef __attribute__((ext_vector_type(8))) short bfrag;   // 8 bf16 (4 VGPRs)
typedef __attribute__((ext_vector_type(4))) float f32x4;
typedef __attribute__((ext_vector_type(4))) int i32x4;

__device__ __forceinline__ uint32_t f2bf(float f) {
  uint32_t u = __builtin_bit_cast(uint32_t, f);
  return (u + 0x7FFFu + ((u >> 16) & 1u)) >> 16;   // RNE f32->bf16 (finite data)
}
__device__ __forceinline__ uint32_t pk(float a, float b) {
  return f2bf(a) | (f2bf(b) << 16);
}

#define MFMA(a, b, c) __builtin_amdgcn_mfma_f32_16x16x32_bf16((a), (b), (c), 0, 0, 0)

__global__ __launch_bounds__(512, 6) void attn_kernel(
    const float* __restrict__ Qg, const float* __restrict__ Kg,
    const float* __restrict__ Vg, const float* __restrict__ Pg,
    float* __restrict__ Sc, float* __restrict__ Ov)
{
  // K slice: [32 s][64 e] bf16, 128B rows, byte ^= (s&7)<<4   (4096 B x2)
  // V slice: [64 d][32 s] bf16, 64B rows,  byte ^= (d&3)<<4   (4096 B x2)
  __shared__ char Kb[2][4096];
  __shared__ char Vb[2][4096];

  const int b = blockIdx.x;
  const int bnh  = ((b >> 4) << 3) | (b & 7);   // pair (b, b+8) -> same bnh, same XCD
  const int half = (b >> 3) & 1;
  const int bn = bnh >> 3, h = bnh & 7;
  const int t = threadIdx.x;
  const int lane = t & 63;
  const int wave = t >> 6;    // 0..7
  const int ql = lane & 15;   // q within 16-tile (MFMA col)
  const int g  = lane >> 4;   // 4-group (MFMA row group / k-slice)
  // balanced q-tile perm: SIMD pair (w, w+4) gets pvmax sums equal
  const int qt = (int)((0x54763210u >> (wave * 4)) & 7);
  const int gqt = half * 8 + qt;
  const int q = gqt * 16 + ql;
  const int pvmax = gqt >> 1;       // causal: PV only for st <= pvmax
  const int vmax = half ? 7 : 3;    // last s-tile whose V this block needs
  const int swzk = (ql & 7) << 4;   // K slice read swizzle (lane-constant)
  const int swzv = (ql & 3) << 4;   // V slice read swizzle
  const float temp = 0.125f;        // 1/sqrt(64)

  // ---- staging roles (512 threads cover each 8KB f32 slice) ----
  const int kr_ = t >> 4;           // K slice row 0..31
  const int kc4 = (t & 15) * 4;     // K f32 col 0..60
  const int vd_ = t & 63;           // V: d
  const int vs4 = (t >> 6) * 4;     // V: s offset 0,4,...,28
  const float* kgp = Kg + (size_t)bn * 131072 + h * 64 + (size_t)kr_ * 512 + kc4;
  const float* vgp = Vg + (size_t)bn * 131072 + h * 64 + (size_t)vs4 * 512 + vd_;
  const int kwoff = (kr_ * 128 + kc4 * 2) ^ ((kr_ & 7) << 4);
  const int vwoff = (vd_ * 64 + vs4 * 2) ^ ((vd_ & 3) << 4);

  // ---- prologue: stage tile 0 into buf 0, then issue tile-1 loads ----
  f32x4 kreg = *(const f32x4*)kgp;
  float vr0 = vgp[0], vr1 = vgp[512], vr2 = vgp[1024], vr3 = vgp[1536];
  {
    uint2 kk; kk.x = pk(kreg[0], kreg[1]); kk.y = pk(kreg[2], kreg[3]);
    *(uint2*)(&Kb[0][0] + kwoff) = kk;
    uint2 vv; vv.x = pk(vr0, vr1); vv.y = pk(vr2, vr3);
    *(uint2*)(&Vb[0][0] + vwoff) = vv;
  }
  kreg = *(const f32x4*)(kgp + 16384);
  vr0 = vgp[16384]; vr1 = vgp[16384 + 512];
  vr2 = vgp[16384 + 1024]; vr3 = vgp[16384 + 1536];

  // ---- Q fragments direct from global (B-operand of swapped QK) ----
  bfrag qf[2];
#pragma unroll
  for (int ks = 0; ks < 2; ++ks) {
    const float* qp = Qg + (size_t)bn * 131072 + (size_t)q * 512 + h * 64 + ks * 32 + g * 8;
    const f32x4 qa = *(const f32x4*)qp;
    const f32x4 qb = *(const f32x4*)(qp + 4);
    union { i32x4 i; bfrag b; } u;
    u.i = i32x4{(int)pk(qa.x, qa.y), (int)pk(qa.z, qa.w),
                (int)pk(qb.x, qb.y), (int)pk(qb.z, qb.w)};
    qf[ks] = u.b;
  }

  f32x4 O[4];
#pragma unroll
  for (int ds = 0; ds < 4; ++ds) O[ds] = f32x4{0.f, 0.f, 0.f, 0.f};
  float m = -1e30f, lsum = 0.f;

  const size_t scb = (size_t)bnh << 16;
  const float* prp = Pg + scb + (size_t)q * 256 + 4 * g;   // + 16*ss + 32*st
  float* scp = Sc + scb + (size_t)q * 256 + 4 * g;

  // prior pipeline: loop-carried scalars, loaded for tile 0 here
  f32x4 pr0 = __builtin_nontemporal_load((const f32x4*)(prp));
  f32x4 pr1 = __builtin_nontemporal_load((const f32x4*)(prp + 16));

  asm volatile("s_waitcnt lgkmcnt(0)" ::: "memory");
  __builtin_amdgcn_s_barrier();

#pragma unroll 1
  for (int st = 0; st < 8; ++st) {
    const int s0 = st * 32;
    const int p = (st & 1) << 12;
    bfrag kf[2][2];
#pragma unroll
    for (int ss = 0; ss < 2; ++ss)
#pragma unroll
      for (int ks = 0; ks < 2; ++ks)
        kf[ss][ks] = *(const bfrag*)(&Kb[0][0] + p +
            (((16 * ss + ql) * 128 + ks * 64 + g * 16) ^ swzk));

    // QK^T swapped -> D[s16][q16]; regs are s-consecutive at fixed q
    f32x4 acc[2];
#pragma unroll
    for (int ss = 0; ss < 2; ++ss) {
      f32x4 a = f32x4{0.f, 0.f, 0.f, 0.f};
      a = MFMA(kf[ss][0], qf[0], a);
      a = MFMA(kf[ss][1], qf[1], a);
      const int sb = s0 + 16 * ss + 4 * g;
      // analytic causal mask: s<=q allowed, else -1e9 (matches input mask)
#pragma unroll
      for (int r = 0; r < 4; ++r)
        a[r] = (sb + r <= q) ? a[r] : a[r] - 1e9f;
      acc[ss] = a + (ss == 0 ? pr0 : pr1);   // scores = QK + mask + prior
    }

    // prior consumed -> issue next tile's loads NOW
    if (st < 7) {
      pr0 = __builtin_nontemporal_load((const f32x4*)(prp + (st + 1) * 32));
      pr1 = __builtin_nontemporal_load((const f32x4*)(prp + (st + 1) * 32 + 16));
    }

    // scores out
    __builtin_nontemporal_store(acc[0], (f32x4*)(scp + s0));
    __builtin_nontemporal_store(acc[1], (f32x4*)(scp + s0 + 16));

    if (st <= pvmax) {  // tiles fully in the causal-masked region skip softmax/PV
      float tm = fmaxf(fmaxf(fmaxf(acc[0][0], acc[0][1]), fmaxf(acc[0][2], acc[0][3])),
                       fmaxf(fmaxf(acc[1][0], acc[1][1]), fmaxf(acc[1][2], acc[1][3])));
      tm = fmaxf(tm, __shfl_xor(tm, 16));
      tm = fmaxf(tm, __shfl_xor(tm, 32));
      tm *= temp;
      const float mnew = fmaxf(m, tm);
      const float fct = __expf(m - mnew);
      m = mnew;
      float pv[8];
#pragma unroll
      for (int ss = 0; ss < 2; ++ss)
#pragma unroll
        for (int r = 0; r < 4; ++r)
          pv[ss * 4 + r] = __expf(fmaf(temp, acc[ss][r], -mnew));
      float ts = (pv[0] + pv[1]) + (pv[2] + pv[3]) + (pv[4] + pv[5]) + (pv[6] + pv[7]);
      ts += __shfl_xor(ts, 16);
      ts += __shfl_xor(ts, 32);
      lsum = lsum * fct + ts;
#pragma unroll
      for (int ds = 0; ds < 4; ++ds) O[ds] *= fct;

      // pack P to bf16 and redistribute in-register to the PV B-fragment
      // layout (lane (ql,g) needs s = s0+8g..8g+7). Held: w0 = s 4g..4g+3,
      // w1 = s 16+4g..+3. Sources: lanes g'={2g&3,(2g+1)&3}, pick w0/w1 by g<2.
      const int w0x = (int)pk(pv[0], pv[1]), w0y = (int)pk(pv[2], pv[3]);
      const int w1x = (int)pk(pv[4], pv[5]), w1y = (int)pk(pv[6], pv[7]);
      const int srcA = ((g & 1) << 5) + ql;       // lane of g' = (2g)&3
      const int a0 = __shfl(w0x, srcA),      a1 = __shfl(w1x, srcA);
      const int b0 = __shfl(w0y, srcA),      b1 = __shfl(w1y, srcA);
      const int c0 = __shfl(w0x, srcA + 16), c1 = __shfl(w1x, srcA + 16);
      const int d0 = __shfl(w0y, srcA + 16), d1 = __shfl(w1y, srcA + 16);
      union { i32x4 i; bfrag b; } pu;
      pu.i = i32x4{g < 2 ? a0 : a1, g < 2 ? b0 : b1,
                   g < 2 ? c0 : c1, g < 2 ? d0 : d1};

      // PV swapped: O^T[d][q] += V^T[d x s32] * P^T[s32 x q16]
      bfrag vf[4];
#pragma unroll
      for (int ds = 0; ds < 4; ++ds)
        vf[ds] = *(const bfrag*)(&Vb[0][0] + p +
            (((16 * ds + ql) * 64 + g * 16) ^ swzv));
#pragma unroll
      for (int ds = 0; ds < 4; ++ds) O[ds] = MFMA(vf[ds], pu.b, O[ds]);
    }

    // write staged K/V regs (tile st+1) into the opposite buffer, then
    // issue tile st+2 loads into the same (now free) regs.
    // V gated by vmax: half-0 blocks never read V tiles 4..7.
    if (st < 7) {
      const int p1 = ((st + 1) & 1) << 12;
      uint2 kk; kk.x = pk(kreg[0], kreg[1]); kk.y = pk(kreg[2], kreg[3]);
      *(uint2*)(&Kb[0][0] + p1 + kwoff) = kk;
      if (st + 1 <= vmax) {
        uint2 vv; vv.x = pk(vr0, vr1); vv.y = pk(vr2, vr3);
        *(uint2*)(&Vb[0][0] + p1 + vwoff) = vv;
      }
      if (st < 6) {
        kreg = *(const f32x4*)(kgp + (size_t)(st + 2) * 16384);
        if (st + 2 <= vmax) {
          vr0 = vgp[(st + 2) * 16384];
          vr1 = vgp[(st + 2) * 16384 + 512];
          vr2 = vgp[(st + 2) * 16384 + 1024];
          vr3 = vgp[(st + 2) * 16384 + 1536];
        }
      }
    }
    asm volatile("s_waitcnt lgkmcnt(0)" ::: "memory");
    __builtin_amdgcn_s_barrier();
  }

  // epilogue: O /= l, store dwordx4 (d-consecutive regs)
  {
    const float inv = 1.f / lsum;
    float* op = Ov + (size_t)bn * 131072 + (size_t)q * 512 + h * 64 + 4 * g;
#pragma unroll
    for (int ds = 0; ds < 4; ++ds) {
      f32x4 o = O[ds] * inv;
      *(f32x4*)(op + 16 * ds) = o;
    }
  }
}

extern "C" void kernel_launch(void* const* d_in, const int* in_sizes, int n_in,
                              void* d_out, int out_size, void* d_ws, size_t ws_size,
                              hipStream_t stream) {
  const float* Qg = (const float*)d_in[0];   // queries  [B,N,L,H,E]
  const float* Kg = (const float*)d_in[1];   // keys     [B,N,S,H,E]
  const float* Vg = (const float*)d_in[2];   // values   [B,N,S,H,D]
  const float* Pg = (const float*)d_in[4];   // attn_scores [B,N,H,L,S]
  float* Sc = (float*)d_out;                            // scores out
  float* Ov = Sc + (size_t)4 * 32 * 8 * 256 * 256;      // V out
  attn_kernel<<<dim3(2048), dim3(512), 0, stream>>>(Qg, Kg, Vg, Pg, Sc, Ov);
}

// Round 12
// 155.112 us; speedup vs baseline: 1.4535x; 1.4535x over previous
//
#include <hip/hip_runtime.h>
#include <stdint.h>

// B=4 N=32 L=S=256 H=8 E=D=64
// grid = B*N*H = 1024 blocks, 1024 threads (16 waves), one (b,n,h) per block.
// Each wave owns 16 q-rows (magic-square permuted q-tile for SIMD balance).
// R11 = R9 structure with 64-column barrier intervals: K/V staged in
// double-buffered 8KB slices (64 rows), 4 intervals x {8 QK MFMA, 4 prior
// loads, 4 score stores, ONE online-softmax update, 8 PV MFMA}. Barriers
// 8 -> 4; per-wave MLP doubled; softmax VALU/shuffle halved. Staging via
// named regs, constant indices (R3/R4 lesson), natural VGPR alloc (1024,2).

typedef __attribute__((ext_vector_type(8))) short bfrag;   // 8 bf16 (4 VGPRs)
typedef __attribute__((ext_vector_type(4))) float f32x4;
typedef __attribute__((ext_vector_type(4))) int i32x4;

__device__ __forceinline__ uint32_t f2bf(float f) {
  uint32_t u = __builtin_bit_cast(uint32_t, f);
  return (u + 0x7FFFu + ((u >> 16) & 1u)) >> 16;   // RNE f32->bf16 (finite data)
}
__device__ __forceinline__ uint32_t pk(float a, float b) {
  return f2bf(a) | (f2bf(b) << 16);
}

#define MFMA(a, b, c) __builtin_amdgcn_mfma_f32_16x16x32_bf16((a), (b), (c), 0, 0, 0)

__global__ __launch_bounds__(1024, 2) void attn_kernel(
    const float* __restrict__ Qg, const float* __restrict__ Kg,
    const float* __restrict__ Vg, const float* __restrict__ Pg,
    float* __restrict__ Sc, float* __restrict__ Ov)
{
  // K slice: [64 s][64 e] bf16, 128B rows, byte ^= (s&7)<<4   (8192 B x2)
  // V slice: [64 d][64 s] bf16, 128B rows, byte ^= (d&7)<<4   (8192 B x2)
  __shared__ char Kb[2][8192];
  __shared__ char Vb[2][8192];

  const int bnh = blockIdx.x;
  const int bn = bnh >> 3, h = bnh & 7;
  const int t = threadIdx.x;
  const int lane = t & 63;
  const int wave = t >> 6;    // 0..15
  const int ql = lane & 15;   // q within 16-tile (MFMA col)
  const int g  = lane >> 4;   // 4-group (MFMA row group / k-slice)
  // magic-square q-tile permutation (per-SIMD PV balance)
  const int qt = (int)((0x783C96D25A1EB4F0ull >> (wave * 4)) & 15);
  const int q = qt * 16 + ql;
  const int pvmax = qt >> 2;        // causal gate in 64-col intervals
  const int swz = (ql & 7) << 4;    // lane-constant read swizzle (K and V)
  const float temp = 0.125f;        // 1/sqrt(64)

  // ---- staging roles ----
  const int kr_ = t >> 4;           // K slice row 0..63
  const int kc4 = (t & 15) * 4;     // K f32 col 0,4,...,60
  const int vd_ = t & 63;           // V: d
  const int vs4 = (t >> 6) * 4;     // V: s offset 0,4,...,60
  const float* kgp = Kg + (size_t)bn * 131072 + h * 64 + (size_t)kr_ * 512 + kc4;
  const float* vgp = Vg + (size_t)bn * 131072 + h * 64 + (size_t)vs4 * 512 + vd_;
  const int kwoff = (kr_ * 128 + kc4 * 2) ^ ((kr_ & 7) << 4);
  const int vwoff = (vd_ * 128 + vs4 * 2) ^ ((vd_ & 7) << 4);

  // ---- prologue: stage interval 0 into buf 0, then issue interval-1 loads ----
  f32x4 kreg = *(const f32x4*)kgp;
  float vr0 = vgp[0], vr1 = vgp[512], vr2 = vgp[1024], vr3 = vgp[1536];
  {
    uint2 kk; kk.x = pk(kreg[0], kreg[1]); kk.y = pk(kreg[2], kreg[3]);
    *(uint2*)(&Kb[0][0] + kwoff) = kk;
    uint2 vv; vv.x = pk(vr0, vr1); vv.y = pk(vr2, vr3);
    *(uint2*)(&Vb[0][0] + vwoff) = vv;
  }
  kreg = *(const f32x4*)(kgp + 32768);
  vr0 = vgp[32768]; vr1 = vgp[32768 + 512];
  vr2 = vgp[32768 + 1024]; vr3 = vgp[32768 + 1536];

  // ---- Q fragments direct from global (B-operand of swapped QK) ----
  bfrag qf[2];
#pragma unroll
  for (int ks = 0; ks < 2; ++ks) {
    const float* qp = Qg + (size_t)bn * 131072 + (size_t)q * 512 + h * 64 + ks * 32 + g * 8;
    const f32x4 qa = *(const f32x4*)qp;
    const f32x4 qb = *(const f32x4*)(qp + 4);
    union { i32x4 i; bfrag b; } u;
    u.i = i32x4{(int)pk(qa.x, qa.y), (int)pk(qa.z, qa.w),
                (int)pk(qb.x, qb.y), (int)pk(qb.z, qb.w)};
    qf[ks] = u.b;
  }

  f32x4 O[4];
#pragma unroll
  for (int ds = 0; ds < 4; ++ds) O[ds] = f32x4{0.f, 0.f, 0.f, 0.f};
  float m = -1e30f, lsum = 0.f;

  const size_t scb = (size_t)bnh << 16;
  const float* prp = Pg + scb + (size_t)q * 256 + 4 * g;   // + 16*j + 64*it
  float* scp = Sc + scb + (size_t)q * 256 + 4 * g;

  // prior pipeline: 4 x f32x4 for the 64-col interval (constant indices only)
  f32x4 pr[4];
#pragma unroll
  for (int j = 0; j < 4; ++j)
    pr[j] = __builtin_nontemporal_load((const f32x4*)(prp + 16 * j));

  asm volatile("s_waitcnt lgkmcnt(0)" ::: "memory");
  __builtin_amdgcn_s_barrier();

#pragma unroll 1
  for (int it = 0; it < 4; ++it) {
    const int s0 = it * 64;
    const int bp = (it & 1) << 13;
    // QK^T swapped over 64 cols: acc[sub][ss], D[s16][q16], col=q
    f32x4 acc[2][2];
#pragma unroll
    for (int sub = 0; sub < 2; ++sub)
#pragma unroll
      for (int ss = 0; ss < 2; ++ss) {
        bfrag kf0 = *(const bfrag*)(&Kb[0][0] + bp +
            (((sub * 32 + 16 * ss + ql) * 128 + 0 * 64 + g * 16) ^ swz));
        bfrag kf1 = *(const bfrag*)(&Kb[0][0] + bp +
            (((sub * 32 + 16 * ss + ql) * 128 + 1 * 64 + g * 16) ^ swz));
        f32x4 a = f32x4{0.f, 0.f, 0.f, 0.f};
        a = MFMA(kf0, qf[0], a);
        a = MFMA(kf1, qf[1], a);
        const int sb = s0 + sub * 32 + 16 * ss + 4 * g;
#pragma unroll
        for (int r = 0; r < 4; ++r)
          a[r] = (sb + r <= q) ? a[r] : a[r] - 1e9f;   // analytic causal mask
        acc[sub][ss] = a + pr[sub * 2 + ss];           // scores = QK+mask+prior
      }

    // prior consumed -> issue next interval's loads NOW
    if (it < 3) {
#pragma unroll
      for (int j = 0; j < 4; ++j)
        pr[j] = __builtin_nontemporal_load(
            (const f32x4*)(prp + (it + 1) * 64 + 16 * j));
    }

    // scores out (4 x dwordx4)
    __builtin_nontemporal_store(acc[0][0], (f32x4*)(scp + s0));
    __builtin_nontemporal_store(acc[0][1], (f32x4*)(scp + s0 + 16));
    __builtin_nontemporal_store(acc[1][0], (f32x4*)(scp + s0 + 32));
    __builtin_nontemporal_store(acc[1][1], (f32x4*)(scp + s0 + 48));

    if (it <= pvmax) {   // ONE online-softmax update per 64-col interval
      float tm = -1e30f;
#pragma unroll
      for (int sub = 0; sub < 2; ++sub)
#pragma unroll
        for (int ss = 0; ss < 2; ++ss)
#pragma unroll
          for (int r = 0; r < 4; ++r) tm = fmaxf(tm, acc[sub][ss][r]);
      tm = fmaxf(tm, __shfl_xor(tm, 16));
      tm = fmaxf(tm, __shfl_xor(tm, 32));
      tm *= temp;
      const float mnew = fmaxf(m, tm);
      const float fct = __expf(m - mnew);
      m = mnew;
      float pv[16];
#pragma unroll
      for (int sub = 0; sub < 2; ++sub)
#pragma unroll
        for (int ss = 0; ss < 2; ++ss)
#pragma unroll
          for (int r = 0; r < 4; ++r)
            pv[sub * 8 + ss * 4 + r] = __expf(fmaf(temp, acc[sub][ss][r], -mnew));
      float ts = 0.f;
#pragma unroll
      for (int j = 0; j < 16; ++j) ts += pv[j];
      ts += __shfl_xor(ts, 16);
      ts += __shfl_xor(ts, 32);
      lsum = lsum * fct + ts;
#pragma unroll
      for (int ds = 0; ds < 4; ++ds) O[ds] *= fct;

      // per 32-col sub-tile: pack P to bf16, redistribute to PV B-fragment
      // layout (lane (ql,g) needs s_loc = 8g..8g+7), then PV MFMA.
#pragma unroll
      for (int sub = 0; sub < 2; ++sub) {
        const int w0x = (int)pk(pv[sub * 8 + 0], pv[sub * 8 + 1]);
        const int w0y = (int)pk(pv[sub * 8 + 2], pv[sub * 8 + 3]);
        const int w1x = (int)pk(pv[sub * 8 + 4], pv[sub * 8 + 5]);
        const int w1y = (int)pk(pv[sub * 8 + 6], pv[sub * 8 + 7]);
        const int srcA = ((g & 1) << 5) + ql;     // lane of g' = (2g)&3
        const int a0 = __shfl(w0x, srcA),      a1 = __shfl(w1x, srcA);
        const int b0 = __shfl(w0y, srcA),      b1 = __shfl(w1y, srcA);
        const int c0 = __shfl(w0x, srcA + 16), c1 = __shfl(w1x, srcA + 16);
        const int d0 = __shfl(w0y, srcA + 16), d1 = __shfl(w1y, srcA + 16);
        union { i32x4 i; bfrag b; } pu;
        pu.i = i32x4{g < 2 ? a0 : a1, g < 2 ? b0 : b1,
                     g < 2 ? c0 : c1, g < 2 ? d0 : d1};
#pragma unroll
        for (int ds = 0; ds < 4; ++ds) {
          bfrag vf = *(const bfrag*)(&Vb[0][0] + bp +
              (((16 * ds + ql) * 128 + sub * 64 + g * 16) ^ swz));
          O[ds] = MFMA(vf, pu.b, O[ds]);
        }
      }
    }

    // write staged K/V regs (interval it+1) into the opposite buffer, then
    // issue interval it+2 loads into the same (now free) regs
    if (it < 3) {
      const int bp1 = ((it + 1) & 1) << 13;
      uint2 kk; kk.x = pk(kreg[0], kreg[1]); kk.y = pk(kreg[2], kreg[3]);
      *(uint2*)(&Kb[0][0] + bp1 + kwoff) = kk;
      uint2 vv; vv.x = pk(vr0, vr1); vv.y = pk(vr2, vr3);
      *(uint2*)(&Vb[0][0] + bp1 + vwoff) = vv;
      if (it < 2) {
        kreg = *(const f32x4*)(kgp + (size_t)(it + 2) * 32768);
        vr0 = vgp[(it + 2) * 32768];
        vr1 = vgp[(it + 2) * 32768 + 512];
        vr2 = vgp[(it + 2) * 32768 + 1024];
        vr3 = vgp[(it + 2) * 32768 + 1536];
      }
    }
    asm volatile("s_waitcnt lgkmcnt(0)" ::: "memory");
    __builtin_amdgcn_s_barrier();
  }

  // epilogue: O /= l, store dwordx4 (d-consecutive regs)
  {
    const float inv = 1.f / lsum;
    float* op = Ov + (size_t)bn * 131072 + (size_t)q * 512 + h * 64 + 4 * g;
#pragma unroll
    for (int ds = 0; ds < 4; ++ds) {
      f32x4 o = O[ds] * inv;
      *(f32x4*)(op + 16 * ds) = o;
    }
  }
}

extern "C" void kernel_launch(void* const* d_in, const int* in_sizes, int n_in,
                              void* d_out, int out_size, void* d_ws, size_t ws_size,
                              hipStream_t stream) {
  const float* Qg = (const float*)d_in[0];   // queries  [B,N,L,H,E]
  const float* Kg = (const float*)d_in[1];   // keys     [B,N,S,H,E]
  const float* Vg = (const float*)d_in[2];   // values   [B,N,S,H,D]
  const float* Pg = (const float*)d_in[4];   // attn_scores [B,N,H,L,S]
  float* Sc = (float*)d_out;                            // scores out
  float* Ov = Sc + (size_t)4 * 32 * 8 * 256 * 256;      // V out
  attn_kernel<<<dim3(1024), dim3(1024), 0, stream>>>(Qg, Kg, Vg, Pg, Sc, Ov);
}